// Round 2
// baseline (431.099 us; speedup 1.0000x reference)
//
#include <hip/hip_runtime.h>

// irreps linear: 256x0e + 128x1o + 64x2e, shared weights, bias on 0e.
// x: (200000, 960) f32; w: 86016 f32; b: 256 f32; out: (200000, 960) f32.
//
// bf16 MFMA 16x16x32, OPERAND-SWAPPED: weights (pre-packed, pre-scaled in ws)
// are the A operand, x-fragments are B. C/D layout (col=lane&15, row=4*lg+j)
// then puts atom-row in l15 and 4 consecutive output channels in the j regs,
// so ALL stores are full float4 (no scalar stride-3/5 scatter -> no RFO).
// Loads are float4 chunks regrouped in-register. No LDS, no barriers.

typedef short frag8 __attribute__((ext_vector_type(8)));   // 8 bf16
typedef float f32x4 __attribute__((ext_vector_type(4)));

static __device__ __forceinline__ short f2bf(float f) {
    union { float f; unsigned u; } v; v.f = f;
    unsigned r = (v.u + 0x7FFFu + ((v.u >> 16) & 1u)) >> 16;  // RNE
    return (short)r;
}

#define MFMA(a, b, c) __builtin_amdgcn_mfma_f32_16x16x32_bf16((a), (b), (c), 0, 0, 0)

// ---- weight prep: identical to round-1 (A[m=w][k=u] == B[k=u][n=w] == W[u][w]).
// frag f, lane l, reg j holds W-element with k = 32*s + 4*(l>>4) + (j&3) + 16*(j>>2),
// w = nt*16 + (l&15).  frag ids: block0 f=nt*8+s (128); block1 128+nt*4+s (32);
// block2 160+nt*2+s (8). 168 frags * 512 bf16 = 86016.
__global__ __launch_bounds__(256) void prep_kernel(const float* __restrict__ w,
                                                   short* __restrict__ wf) {
    int e = blockIdx.x * 256 + threadIdx.x;   // 0..86015
    int f = e >> 9;
    int r = e & 511;
    int l = r >> 3, j = r & 7;
    int l15 = l & 15, lg = l >> 4;
    int kk = 4 * lg + (j & 3) + 16 * (j >> 2);   // k within 32-window
    int u, wc, woff, mul; float scale;
    if (f < 128) {
        int nt = f >> 3, s = f & 7;
        u = 32 * s + kk; wc = nt * 16 + l15; woff = 0;     mul = 256; scale = 0.0625f;
    } else if (f < 160) {
        int g = f - 128, nt = g >> 2, s = g & 3;
        u = 32 * s + kk; wc = nt * 16 + l15; woff = 65536; mul = 128; scale = 0.088388347648318447f;
    } else {
        int g = f - 160, nt = g >> 1, s = g & 1;
        u = 32 * s + kk; wc = nt * 16 + l15; woff = 81920; mul = 64;  scale = 0.125f;
    }
    wf[e] = f2bf(scale * w[woff + u * mul + wc]);
}

// ---- main kernel: 4 independent waves per block, 16 rows per wave ----
__global__ __launch_bounds__(256) void lin_main(const float* __restrict__ x,
                                                const short* __restrict__ wf,
                                                const float* __restrict__ bias,
                                                float* __restrict__ out) {
    const int lane = threadIdx.x & 63;
    const int wv   = threadIdx.x >> 6;
    const int l15  = lane & 15;
    const int lg   = lane >> 4;
    const long row0 = ((long)blockIdx.x * 4 + wv) * 16;
    const float* __restrict__ xr   = x   + row0 * 960 + (long)l15 * 960;
    float* __restrict__       outr = out + row0 * 960 + (long)l15 * 960;
    const frag8* __restrict__ wfr  = (const frag8*)wf;

    // ================= block 0 : cols 0..255, K=256 =================
    frag8 a0[8];
    {
        const float* p = xr + 4 * lg;
        #pragma unroll
        for (int s = 0; s < 8; ++s) {
            const f32x4 v0 = *(const f32x4*)(p + 32 * s);
            const f32x4 v1 = *(const f32x4*)(p + 32 * s + 16);
            frag8 a;
            a[0] = f2bf(v0[0]); a[1] = f2bf(v0[1]); a[2] = f2bf(v0[2]); a[3] = f2bf(v0[3]);
            a[4] = f2bf(v1[0]); a[5] = f2bf(v1[1]); a[6] = f2bf(v1[2]); a[7] = f2bf(v1[3]);
            a0[s] = a;
        }
    }
    #pragma unroll 4
    for (int nt = 0; nt < 16; ++nt) {
        f32x4 acc = {0.f, 0.f, 0.f, 0.f};
        #pragma unroll
        for (int s = 0; s < 8; ++s) {
            frag8 bw = wfr[(nt * 8 + s) * 64 + lane];
            acc = MFMA(bw, a0[s], acc);          // D[w][atom]
        }
        const f32x4 bv = *(const f32x4*)(bias + nt * 16 + 4 * lg);
        f32x4 st = {acc[0] + bv[0], acc[1] + bv[1], acc[2] + bv[2], acc[3] + bv[3]};
        *(f32x4*)(outr + nt * 16 + 4 * lg) = st;
    }

    // ================= block 1 : cols 256..639 (col = 256 + 3u + i) =====
    // Per (s,h): 12 consecutive floats at col 256 + 3*(32s+16h+4lg),
    // regrouped into a1[i*4+s] regs 4h..4h+3 (element (delta,i) at idx 3*delta+i).
    frag8 a1[12];
    #pragma unroll
    for (int s = 0; s < 4; ++s) {
        #pragma unroll
        for (int h = 0; h < 2; ++h) {
            const float* p = xr + 256 + 3 * (32 * s + 16 * h + 4 * lg);
            const f32x4 q0 = *(const f32x4*)(p);
            const f32x4 q1 = *(const f32x4*)(p + 4);
            const f32x4 q2 = *(const f32x4*)(p + 8);
            const int j0 = 4 * h;
            a1[0 + s][j0 + 0] = f2bf(q0[0]); a1[0 + s][j0 + 1] = f2bf(q0[3]);
            a1[0 + s][j0 + 2] = f2bf(q1[2]); a1[0 + s][j0 + 3] = f2bf(q2[1]);
            a1[4 + s][j0 + 0] = f2bf(q0[1]); a1[4 + s][j0 + 1] = f2bf(q1[0]);
            a1[4 + s][j0 + 2] = f2bf(q1[3]); a1[4 + s][j0 + 3] = f2bf(q2[2]);
            a1[8 + s][j0 + 0] = f2bf(q0[2]); a1[8 + s][j0 + 1] = f2bf(q1[1]);
            a1[8 + s][j0 + 2] = f2bf(q2[0]); a1[8 + s][j0 + 3] = f2bf(q2[3]);
        }
    }
    #pragma unroll 2
    for (int nt = 0; nt < 8; ++nt) {
        f32x4 c0 = {0.f,0.f,0.f,0.f}, c1 = {0.f,0.f,0.f,0.f}, c2 = {0.f,0.f,0.f,0.f};
        #pragma unroll
        for (int s = 0; s < 4; ++s) {
            frag8 bw = wfr[(128 + nt * 4 + s) * 64 + lane];
            c0 = MFMA(bw, a1[0 + s], c0);
            c1 = MFMA(bw, a1[4 + s], c1);
            c2 = MFMA(bw, a1[8 + s], c2);
        }
        // lane holds 12 consecutive floats: (j,i) at 3j+i, base col 256+3*(nt*16+4lg)
        float* o = outr + 256 + 3 * (nt * 16 + 4 * lg);
        f32x4 v0 = {c0[0], c1[0], c2[0], c0[1]};
        f32x4 v1 = {c1[1], c2[1], c0[2], c1[2]};
        f32x4 v2 = {c2[2], c0[3], c1[3], c2[3]};
        *(f32x4*)(o)     = v0;
        *(f32x4*)(o + 4) = v1;
        *(f32x4*)(o + 8) = v2;
    }

    // ================= block 2 : cols 640..959 (col = 640 + 5u + i) =====
    // Per (s,h): 20 consecutive floats at col 640 + 5*(32s+16h+4lg),
    // element (delta,i) at idx 5*delta+i -> a2[i*2+s] reg 4h+delta.
    frag8 a2[10];
    #pragma unroll
    for (int s = 0; s < 2; ++s) {
        #pragma unroll
        for (int h = 0; h < 2; ++h) {
            const float* p = xr + 640 + 5 * (32 * s + 16 * h + 4 * lg);
            const f32x4 q0 = *(const f32x4*)(p);
            const f32x4 q1 = *(const f32x4*)(p + 4);
            const f32x4 q2 = *(const f32x4*)(p + 8);
            const f32x4 q3 = *(const f32x4*)(p + 12);
            const f32x4 q4 = *(const f32x4*)(p + 16);
            const int j0 = 4 * h;
            a2[0 + s][j0 + 0] = f2bf(q0[0]); a2[0 + s][j0 + 1] = f2bf(q1[1]);
            a2[0 + s][j0 + 2] = f2bf(q2[2]); a2[0 + s][j0 + 3] = f2bf(q3[3]);
            a2[2 + s][j0 + 0] = f2bf(q0[1]); a2[2 + s][j0 + 1] = f2bf(q1[2]);
            a2[2 + s][j0 + 2] = f2bf(q2[3]); a2[2 + s][j0 + 3] = f2bf(q4[0]);
            a2[4 + s][j0 + 0] = f2bf(q0[2]); a2[4 + s][j0 + 1] = f2bf(q1[3]);
            a2[4 + s][j0 + 2] = f2bf(q3[0]); a2[4 + s][j0 + 3] = f2bf(q4[1]);
            a2[6 + s][j0 + 0] = f2bf(q0[3]); a2[6 + s][j0 + 1] = f2bf(q2[0]);
            a2[6 + s][j0 + 2] = f2bf(q3[1]); a2[6 + s][j0 + 3] = f2bf(q4[2]);
            a2[8 + s][j0 + 0] = f2bf(q1[0]); a2[8 + s][j0 + 1] = f2bf(q2[1]);
            a2[8 + s][j0 + 2] = f2bf(q3[2]); a2[8 + s][j0 + 3] = f2bf(q4[3]);
        }
    }
    #pragma unroll 2
    for (int nt = 0; nt < 4; ++nt) {
        f32x4 c0 = {0.f,0.f,0.f,0.f}, c1 = {0.f,0.f,0.f,0.f}, c2 = {0.f,0.f,0.f,0.f},
              c3 = {0.f,0.f,0.f,0.f}, c4 = {0.f,0.f,0.f,0.f};
        #pragma unroll
        for (int s = 0; s < 2; ++s) {
            frag8 bw = wfr[(160 + nt * 2 + s) * 64 + lane];
            c0 = MFMA(bw, a2[0 + s], c0);
            c1 = MFMA(bw, a2[2 + s], c1);
            c2 = MFMA(bw, a2[4 + s], c2);
            c3 = MFMA(bw, a2[6 + s], c3);
            c4 = MFMA(bw, a2[8 + s], c4);
        }
        // lane holds 20 consecutive floats: (j,i) at 5j+i, base 640+5*(nt*16+4lg)
        float* o = outr + 640 + 5 * (nt * 16 + 4 * lg);
        f32x4 v0 = {c0[0], c1[0], c2[0], c3[0]};
        f32x4 v1 = {c4[0], c0[1], c1[1], c2[1]};
        f32x4 v2 = {c3[1], c4[1], c0[2], c1[2]};
        f32x4 v3 = {c2[2], c3[2], c4[2], c0[3]};
        f32x4 v4 = {c1[3], c2[3], c3[3], c4[3]};
        *(f32x4*)(o)      = v0;
        *(f32x4*)(o + 4)  = v1;
        *(f32x4*)(o + 8)  = v2;
        *(f32x4*)(o + 12) = v3;
        *(f32x4*)(o + 16) = v4;
    }
}

extern "C" void kernel_launch(void* const* d_in, const int* in_sizes, int n_in,
                              void* d_out, int out_size, void* d_ws, size_t ws_size,
                              hipStream_t stream) {
    const float* x = (const float*)d_in[0];
    const float* w = (const float*)d_in[1];
    const float* b = (const float*)d_in[2];
    float* out = (float*)d_out;
    short* wf  = (short*)d_ws;          // 86016 bf16 = 172032 B of scratch

    hipLaunchKernelGGL(prep_kernel, dim3(336), dim3(256), 0, stream, w, wf);
    // 200000 rows = 3125 blocks * 4 waves * 16 rows, exact.
    hipLaunchKernelGGL(lin_main, dim3(3125), dim3(256), 0, stream, x, wf, b, out);
}